// Round 14
// baseline (362.186 us; speedup 1.0000x reference)
//
#include <hip/hip_runtime.h>
#include <math.h>

typedef __attribute__((ext_vector_type(8))) __bf16 bf16x8;
typedef __attribute__((ext_vector_type(4))) float f32x4;
typedef __attribute__((ext_vector_type(4))) unsigned short us4;
typedef unsigned short u16;
typedef unsigned int u32;

#define DEVI static __device__ __forceinline__

// round-to-nearest-even fp32 -> bf16
DEVI u16 f2bf(float f) {
  union { float f; unsigned u; } v; v.f = f;
  unsigned r = v.u + 0x7fffu + ((v.u >> 16) & 1u);
  return (u16)(r >> 16);
}

DEVI void async16(const void* g, void* l) {
  __builtin_amdgcn_global_load_lds((const __attribute__((address_space(1))) void*)g,
                                   (__attribute__((address_space(3))) void*)l, 16, 0, 0);
}

// pack two f32 -> one u32 of 2 bf16 (RNE)
DEVI u32 pkbf(float lo, float hi) {
  u32 r;
  asm("v_cvt_pk_bf16_f32 %0, %1, %2" : "=v"(r) : "v"(lo), "v"(hi));
  return r;
}

// ---------------- fused cast fp32 -> bf16 (x + 4 weights, one launch) -------
__global__ __launch_bounds__(256)
void cast_all(const float* __restrict__ x,
              const float* __restrict__ wq, const float* __restrict__ wk,
              const float* __restrict__ wv, const float* __restrict__ wo,
              u16* __restrict__ xb, u16* __restrict__ wqb, u16* __restrict__ wkb,
              u16* __restrict__ wvb, u16* __restrict__ wob)
{
  const int NX = 4096 * 2048, NW = 2048 * 2048;
  int i = (blockIdx.x * 256 + threadIdx.x) * 4;
  const float* src; u16* dst; int off;
  if (i < NX)               { src = x;  dst = xb;  off = i; }
  else if (i < NX + NW)     { src = wq; dst = wqb; off = i - NX; }
  else if (i < NX + 2 * NW) { src = wk; dst = wkb; off = i - NX - NW; }
  else if (i < NX + 3 * NW) { src = wv; dst = wvb; off = i - NX - 2 * NW; }
  else                      { src = wo; dst = wob; off = i - NX - 3 * NW; }
  float4 v = *(const float4*)(src + off);
  us4 o = { f2bf(v.x), f2bf(v.y), f2bf(v.z), f2bf(v.w) };
  *(us4*)(dst + off) = o;
}

// ---------------- GEMM: C[m,n] = sum_k A[m,k]*B[n,k] (+bias) ----------------
// m97 template, BK=64 (R11-proven ~37us): 128x128 tile, 4 waves, 2-barrier
// K-loop, global_load_lds width-16, LDS [128][64] XOR-swizzled (row&7)<<4
// via inverse-swizzled GLOBAL source + linear LDS dest (G21).
// MODE 0: Q -> rope*(1/sqrt(128)*log2e); 1: K rope+swz; 2: V transp+perm+swz;
// MODE 3: O -> fp32 + bias
template<int MODE>
__global__ __launch_bounds__(256, 3)
void gemm_bt(const u16* __restrict__ A, const u16* __restrict__ B,
             const float* __restrict__ bias,
             const float* __restrict__ cosT, const float* __restrict__ sinT,
             void* __restrict__ outp)
{
  __shared__ __align__(16) u16 As[8192];   // [128][64] swizzled
  __shared__ __align__(16) u16 Bs[8192];
  const int t = threadIdx.x, w = t >> 6, lane = t & 63;
  const int lrow = lane & 15, lk8 = (lane >> 4) * 8;
  const int brow = blockIdx.y * 128, bcol = blockIdx.x * 128;
  const int wr = (w >> 1) * 64, wc = (w & 1) * 64;

  u32 sA[4], sB[4];
#pragma unroll
  for (int r = 0; r < 4; ++r) {
    const int q = (r * 256 + t) * 16;
    const int row = q >> 7;
    const int cb = (q ^ ((row & 7) << 4)) & 127;   // logical col byte
    sA[r] = (u32)((brow + row) * 2048 + (cb >> 1));
    sB[r] = (u32)((bcol + row) * 2048 + (cb >> 1));
  }

  int offA[4][2], offB[4][2];
#pragma unroll
  for (int m = 0; m < 4; ++m)
#pragma unroll
    for (int kk = 0; kk < 2; ++kk) {
      int row = wr + m * 16 + lrow;
      offA[m][kk] = (row * 128 + (kk * 32 + lk8) * 2) ^ ((row & 7) << 4);
      row = wc + m * 16 + lrow;
      offB[m][kk] = (row * 128 + (kk * 32 + lk8) * 2) ^ ((row & 7) << 4);
    }

  f32x4 acc[4][4] = {};

  for (int k0 = 0; k0 < 2048; k0 += 64) {
#pragma unroll
    for (int r = 0; r < 4; ++r) {
      async16(A + sA[r] + k0, (char*)As + (r * 256 + t) * 16);
      async16(B + sB[r] + k0, (char*)Bs + (r * 256 + t) * 16);
    }
    __syncthreads();
#pragma unroll
    for (int kk = 0; kk < 2; ++kk) {
      bf16x8 a[4], b[4];
#pragma unroll
      for (int m = 0; m < 4; ++m) a[m] = *(const bf16x8*)((char*)As + offA[m][kk]);
#pragma unroll
      for (int n = 0; n < 4; ++n) b[n] = *(const bf16x8*)((char*)Bs + offB[n][kk]);
#pragma unroll
      for (int m = 0; m < 4; ++m)
#pragma unroll
        for (int n = 0; n < 4; ++n)
          acc[m][n] = __builtin_amdgcn_mfma_f32_16x16x32_bf16(a[m], b[n], acc[m][n], 0, 0, 0);
    }
    __syncthreads();
  }

  // epilogue: C/D layout col = lane&15, row = (lane>>4)*4 + r
#pragma unroll
  for (int mi = 0; mi < 4; ++mi) {
#pragma unroll
    for (int ni = 0; ni < 4; ++ni) {
      f32x4 v = acc[mi][ni];
      const int row0 = brow + wr + mi * 16 + (lane >> 4) * 4;
      const int col = bcol + wc + ni * 16 + lrow;
      if constexpr (MODE == 3) {
        float* O = (float*)outp;
        const float bv = bias[col];
#pragma unroll
        for (int r = 0; r < 4; ++r)
          O[(size_t)(row0 + r) * 2048 + col] = v[r] + bv;
      } else if constexpr (MODE == 0 || MODE == 1) {
        u16* O = (u16*)outp;
        const float bv = bias[col];
        const int h = col >> 7, d = col & 127;
        const float sgn = (d & 1) ? 1.f : -1.f;
        const float QSCL = 0.08838834764831845f * 1.44269504088896340f;
#pragma unroll
        for (int r = 0; r < 4; ++r) {
          const int row = row0 + r, bb = row >> 11, s = row & 2047;
          float q = v[r] + bv;
          float p = __shfl_xor(q, 1);   // partner dim d^1 lives in lane^1
          float o = q * cosT[s * 128 + d] + sgn * p * sinT[s * 128 + d];
          if constexpr (MODE == 0) o *= QSCL;
          u16* base = O + ((size_t)(bb * 16 + h) * 2048 + s) * 128;
          if constexpr (MODE == 0) {
            base[d] = f2bf(o);
          } else {
            *(u16*)((char*)base + (((unsigned)(d << 1)) ^ (unsigned)((s & 7) << 4))) = f2bf(o);
          }
        }
      } else { // MODE 2: V -> Vt [B,H,HD,S], pi-permuted within each 64-col block
        u16* O = (u16*)outp;
        const float bv = bias[col];
        const int h = col >> 7, d = col & 127;
        const int bb = row0 >> 11, s = row0 & 2047;
        us4 ov;
#pragma unroll
        for (int r = 0; r < 4; ++r) ov[r] = f2bf(v[r] + bv);
        const int l = s & 63;
        const int kt = l >> 4, g2 = (l >> 2) & 3;
        const int c = ((kt >> 1) << 5) + (g2 << 3) + ((kt & 1) << 2);
        u16* base = O + ((size_t)(bb * 16 + h) * 128 + d) * 2048 + (s & ~63);
        *(us4*)((char*)base + ((unsigned)(c << 1) ^ (unsigned)((d & 7) << 4))) = ov;
      }
    }
  }
}

// -------- causal flash attention: 8-wave blocks (R5 per-wave code) ----------
// Q: [BH][S][128] bf16 pre-scaled by 1/sqrt(128)*log2e, K: row-swizzled,
// Vt: [BH][128][S] pi-permuted + swizzled. AO out: [4096][2048] bf16.
// Block = 8 waves x 16 q = 128-row q-tile; folded pairing {p, 15-p} ->
// uniform 34 KV-iters. 512 blocks x 512 thr = 2 blocks/CU = 16 waves/CU
// (4 waves/SIMD, 2x R5's TLP). Per-wave compute identical to R5.
__global__ __launch_bounds__(512, 4)
void attn_fwd(const u16* __restrict__ Q, const u16* __restrict__ K,
              const u16* __restrict__ Vt, u16* __restrict__ AO)
{
  __shared__ __align__(16) u16 Ks[2][64 * 128];
  __shared__ __align__(16) u16 Vs[2][128 * 64];
  const int t = threadIdx.x, w = t >> 6, lane = t & 63;
  const int lrow = lane & 15, g = lane >> 4, lk8 = g * 8;
  const int id = blockIdx.x;
  const int bh = (id & 7) | (((id >> 3) & 3) << 3);   // XCD-local bh grouping
  const int pr = id >> 5;                              // pair index 0..15
  const u16* Qg = Q + (size_t)bh * 2048 * 128;
  const u16* Kg = K + (size_t)bh * 2048 * 128;
  const u16* Vg = Vt + (size_t)bh * 128 * 2048;
  const int bb = bh >> 4, h = bh & 15;

  auto stage = [&](int i, int b) {
#pragma unroll
    for (int r = 0; r < 2; ++r) {
      int e = (r * 512 + t) * 8;
      async16(Kg + (size_t)i * 8192 + e, &Ks[b][e]);
      async16(Vg + (size_t)(e >> 6) * 2048 + i * 64 + (e & 63), &Vs[b][e]);
    }
  };

  for (int half = 0; half < 2; ++half) {
    const int qt = half ? (15 - pr) : pr;     // 128-row q-tile index
    const int qw = qt * 128 + w * 16;         // this wave's 16 q-rows
    const int nkv = 2 * qt + 2;
    const int qg = qw + lrow;                 // this lane's q-row

    bf16x8 qf[4];
#pragma unroll
    for (int c = 0; c < 4; ++c)
      qf[c] = *(const bf16x8*)(Qg + (size_t)(qw + lrow) * 128 + lk8 + c * 32);

    f32x4 acc_o[8] = {};
    float m = -1e30f, lsum = 0.f;

    stage(0, 0);
    for (int i = 0; i < nkv; ++i) {
      const int cur = i & 1;
      const bool pfch = (i + 1) < nkv;
      if (pfch) stage(i + 1, cur ^ 1);
      if (pfch) asm volatile("s_waitcnt vmcnt(4)" ::: "memory");
      else      asm volatile("s_waitcnt vmcnt(0)" ::: "memory");
      __builtin_amdgcn_s_barrier();
      __builtin_amdgcn_sched_barrier(0);

      // QK^T swapped: C col = q (lane&15), row = k
      f32x4 sc[4];
      __builtin_amdgcn_s_setprio(1);
#pragma unroll
      for (int kt = 0; kt < 4; ++kt) {
        f32x4 s = {};
        const int krow = kt * 16 + lrow;
        const char* kbase = (const char*)(&Ks[cur][krow * 128]);
        const unsigned sw = (unsigned)((krow & 7) << 4);
#pragma unroll
        for (int c = 0; c < 4; ++c) {
          bf16x8 kf = *(const bf16x8*)(kbase + ((unsigned)((lk8 + c * 32) << 1) ^ sw));
          s = __builtin_amdgcn_mfma_f32_16x16x32_bf16(kf, qf[c], s, 0, 0, 0);
        }
        sc[kt] = s;
      }
      __builtin_amdgcn_s_setprio(0);

      float p[4][4];
      const bool guard = (i * 64 + 63) > qw;   // kv-tile reaches this wave's rows
      if (guard) {
#pragma unroll
        for (int kt = 0; kt < 4; ++kt)
#pragma unroll
          for (int r = 0; r < 4; ++r) {
            int kg = i * 64 + kt * 16 + g * 4 + r;
            p[kt][r] = (kg > qg) ? -1e30f : sc[kt][r];
          }
      } else {
#pragma unroll
        for (int kt = 0; kt < 4; ++kt)
#pragma unroll
          for (int r = 0; r < 4; ++r) p[kt][r] = sc[kt][r];
      }

      float mm = p[0][0];
#pragma unroll
      for (int kt = 0; kt < 4; ++kt)
#pragma unroll
        for (int r = 0; r < 4; ++r) mm = fmaxf(mm, p[kt][r]);
      mm = fmaxf(mm, __shfl_xor(mm, 16));
      mm = fmaxf(mm, __shfl_xor(mm, 32));

      float rs = 0.f;
      if (__any(mm > m + 8.f)) {
        const float mn = fmaxf(m, mm);
        const float corr = exp2f(m - mn);
        m = mn;
#pragma unroll
        for (int kt = 0; kt < 4; ++kt)
#pragma unroll
          for (int r = 0; r < 4; ++r) { p[kt][r] = exp2f(p[kt][r] - m); rs += p[kt][r]; }
        rs += __shfl_xor(rs, 16);
        rs += __shfl_xor(rs, 32);
        lsum = lsum * corr + rs;
#pragma unroll
        for (int nt = 0; nt < 8; ++nt)
#pragma unroll
          for (int r = 0; r < 4; ++r) acc_o[nt][r] *= corr;
      } else {
#pragma unroll
        for (int kt = 0; kt < 4; ++kt)
#pragma unroll
          for (int r = 0; r < 4; ++r) { p[kt][r] = exp2f(p[kt][r] - m); rs += p[kt][r]; }
        rs += __shfl_xor(rs, 16);
        rs += __shfl_xor(rs, 32);
        lsum += rs;
      }

      bf16x8 pb[2];
#pragma unroll
      for (int kc = 0; kc < 2; ++kc) {
        union { u32 d[4]; bf16x8 v; } u;
        u.d[0] = pkbf(p[2 * kc][0], p[2 * kc][1]);
        u.d[1] = pkbf(p[2 * kc][2], p[2 * kc][3]);
        u.d[2] = pkbf(p[2 * kc + 1][0], p[2 * kc + 1][1]);
        u.d[3] = pkbf(p[2 * kc + 1][2], p[2 * kc + 1][3]);
        pb[kc] = u.v;
      }

      __builtin_amdgcn_s_setprio(1);
#pragma unroll
      for (int nt = 0; nt < 8; ++nt) {
        const int vrow = nt * 16 + lrow;
        const char* vbase = (const char*)(&Vs[cur][vrow * 64]);
        const unsigned sw2 = (unsigned)((vrow & 7) << 4);
#pragma unroll
        for (int kc = 0; kc < 2; ++kc) {
          bf16x8 vf = *(const bf16x8*)(vbase + ((unsigned)((lk8 + kc * 32) << 1) ^ sw2));
          acc_o[nt] = __builtin_amdgcn_mfma_f32_16x16x32_bf16(vf, pb[kc], acc_o[nt], 0, 0, 0);
        }
      }
      __builtin_amdgcn_s_setprio(0);
      __builtin_amdgcn_s_barrier();
    }

    const float inv_l = 1.f / lsum;
#pragma unroll
    for (int nt = 0; nt < 8; ++nt) {
      us4 ov;
#pragma unroll
      for (int r = 0; r < 4; ++r) ov[r] = f2bf(acc_o[nt][r] * inv_l);
      *(us4*)(AO + ((size_t)(bb * 2048 + qg)) * 2048 + h * 128 + nt * 16 + g * 4) = ov;
    }
  }
}

// ---------------- launch ----------------
extern "C" void kernel_launch(void* const* d_in, const int* in_sizes, int n_in,
                              void* d_out, int out_size, void* d_ws, size_t ws_size,
                              hipStream_t stream) {
  const float* x    = (const float*)d_in[0];
  const float* cosT = (const float*)d_in[1];
  const float* sinT = (const float*)d_in[2];
  const float* Wq   = (const float*)d_in[4];
  const float* bq   = (const float*)d_in[5];
  const float* Wk   = (const float*)d_in[6];
  const float* bk   = (const float*)d_in[7];
  const float* Wv   = (const float*)d_in[8];
  const float* bv   = (const float*)d_in[9];
  const float* Wo   = (const float*)d_in[10];
  const float* bo   = (const float*)d_in[11];
  float* out = (float*)d_out;

  char* ws = (char*)d_ws;
  u16* xb  = (u16*)(ws);                    // 16 MB  [4096][2048]
  u16* Wqb = (u16*)(ws + (16u << 20));      // 8 MB
  u16* Wkb = (u16*)(ws + (24u << 20));
  u16* Wvb = (u16*)(ws + (32u << 20));
  u16* Wob = (u16*)(ws + (40u << 20));
  u16* Qb  = (u16*)(ws + (48u << 20));      // 16 MB [BH][S][HD] (pre-scaled)
  u16* Kb  = (u16*)(ws + (64u << 20));      // 16 MB [BH][S][HD] swizzled
  u16* Vtb = (u16*)(ws + (80u << 20));      // 16 MB [BH][HD][S] permuted+swizzled
  u16* AOb = (u16*)(ws + (96u << 20));      // 16 MB [4096][2048]

  // one fused cast: x + 4 weights (25.17M elems / 4 per thread)
  cast_all<<<24576, 256, 0, stream>>>(x, Wq, Wk, Wv, Wo, xb, Wqb, Wkb, Wvb, Wob);

  dim3 gg(16, 32);  // N/128, M/128
  gemm_bt<0><<<gg, 256, 0, stream>>>(xb, Wqb, bq, cosT, sinT, (void*)Qb);
  gemm_bt<1><<<gg, 256, 0, stream>>>(xb, Wkb, bk, cosT, sinT, (void*)Kb);
  gemm_bt<2><<<gg, 256, 0, stream>>>(xb, Wvb, bv, nullptr, nullptr, (void*)Vtb);

  attn_fwd<<<512, 512, 0, stream>>>(Qb, Kb, Vtb, AOb);

  gemm_bt<3><<<gg, 256, 0, stream>>>(AOb, Wob, bo, nullptr, nullptr, (void*)out);
}

// Round 15
// 317.474 us; speedup vs baseline: 1.1408x; 1.1408x over previous
//
#include <hip/hip_runtime.h>
#include <math.h>

typedef __attribute__((ext_vector_type(8))) __bf16 bf16x8;
typedef __attribute__((ext_vector_type(4))) float f32x4;
typedef __attribute__((ext_vector_type(4))) unsigned short us4;
typedef unsigned short u16;
typedef unsigned int u32;

#define DEVI static __device__ __forceinline__

// round-to-nearest-even fp32 -> bf16
DEVI u16 f2bf(float f) {
  union { float f; unsigned u; } v; v.f = f;
  unsigned r = v.u + 0x7fffu + ((v.u >> 16) & 1u);
  return (u16)(r >> 16);
}

DEVI void async16(const void* g, void* l) {
  __builtin_amdgcn_global_load_lds((const __attribute__((address_space(1))) void*)g,
                                   (__attribute__((address_space(3))) void*)l, 16, 0, 0);
}

// pack two f32 -> one u32 of 2 bf16 (RNE)
DEVI u32 pkbf(float lo, float hi) {
  u32 r;
  asm("v_cvt_pk_bf16_f32 %0, %1, %2" : "=v"(r) : "v"(lo), "v"(hi));
  return r;
}

// ---------------- fused cast fp32 -> bf16 (x + 4 weights, one launch) -------
__global__ __launch_bounds__(256)
void cast_all(const float* __restrict__ x,
              const float* __restrict__ wq, const float* __restrict__ wk,
              const float* __restrict__ wv, const float* __restrict__ wo,
              u16* __restrict__ xb, u16* __restrict__ wqb, u16* __restrict__ wkb,
              u16* __restrict__ wvb, u16* __restrict__ wob)
{
  const int NX = 4096 * 2048, NW = 2048 * 2048;
  int i = (blockIdx.x * 256 + threadIdx.x) * 4;
  const float* src; u16* dst; int off;
  if (i < NX)               { src = x;  dst = xb;  off = i; }
  else if (i < NX + NW)     { src = wq; dst = wqb; off = i - NX; }
  else if (i < NX + 2 * NW) { src = wk; dst = wkb; off = i - NX - NW; }
  else if (i < NX + 3 * NW) { src = wv; dst = wvb; off = i - NX - 2 * NW; }
  else                      { src = wo; dst = wob; off = i - NX - 3 * NW; }
  float4 v = *(const float4*)(src + off);
  us4 o = { f2bf(v.x), f2bf(v.y), f2bf(v.z), f2bf(v.w) };
  *(us4*)(dst + off) = o;
}

// ---------------- GEMM: C[m,n] = sum_k A[m,k]*B[n,k] (+bias) ----------------
// m97 template, BK=64 (R11-proven ~37us): 128x128 tile, 4 waves, 2-barrier
// K-loop, global_load_lds width-16, LDS [128][64] XOR-swizzled (row&7)<<4
// via inverse-swizzled GLOBAL source + linear LDS dest (G21).
// MODE 0: Q -> rope*(1/sqrt(128)*log2e); 1: K rope+swz; 2: V transp+perm+swz;
// MODE 3: O -> fp32 + bias
template<int MODE>
__global__ __launch_bounds__(256, 3)
void gemm_bt(const u16* __restrict__ A, const u16* __restrict__ B,
             const float* __restrict__ bias,
             const float* __restrict__ cosT, const float* __restrict__ sinT,
             void* __restrict__ outp)
{
  __shared__ __align__(16) u16 As[8192];   // [128][64] swizzled
  __shared__ __align__(16) u16 Bs[8192];
  const int t = threadIdx.x, w = t >> 6, lane = t & 63;
  const int lrow = lane & 15, lk8 = (lane >> 4) * 8;
  const int brow = blockIdx.y * 128, bcol = blockIdx.x * 128;
  const int wr = (w >> 1) * 64, wc = (w & 1) * 64;

  u32 sA[4], sB[4];
#pragma unroll
  for (int r = 0; r < 4; ++r) {
    const int q = (r * 256 + t) * 16;
    const int row = q >> 7;
    const int cb = (q ^ ((row & 7) << 4)) & 127;   // logical col byte
    sA[r] = (u32)((brow + row) * 2048 + (cb >> 1));
    sB[r] = (u32)((bcol + row) * 2048 + (cb >> 1));
  }

  int offA[4][2], offB[4][2];
#pragma unroll
  for (int m = 0; m < 4; ++m)
#pragma unroll
    for (int kk = 0; kk < 2; ++kk) {
      int row = wr + m * 16 + lrow;
      offA[m][kk] = (row * 128 + (kk * 32 + lk8) * 2) ^ ((row & 7) << 4);
      row = wc + m * 16 + lrow;
      offB[m][kk] = (row * 128 + (kk * 32 + lk8) * 2) ^ ((row & 7) << 4);
    }

  f32x4 acc[4][4] = {};

  for (int k0 = 0; k0 < 2048; k0 += 64) {
#pragma unroll
    for (int r = 0; r < 4; ++r) {
      async16(A + sA[r] + k0, (char*)As + (r * 256 + t) * 16);
      async16(B + sB[r] + k0, (char*)Bs + (r * 256 + t) * 16);
    }
    __syncthreads();
#pragma unroll
    for (int kk = 0; kk < 2; ++kk) {
      bf16x8 a[4], b[4];
#pragma unroll
      for (int m = 0; m < 4; ++m) a[m] = *(const bf16x8*)((char*)As + offA[m][kk]);
#pragma unroll
      for (int n = 0; n < 4; ++n) b[n] = *(const bf16x8*)((char*)Bs + offB[n][kk]);
#pragma unroll
      for (int m = 0; m < 4; ++m)
#pragma unroll
        for (int n = 0; n < 4; ++n)
          acc[m][n] = __builtin_amdgcn_mfma_f32_16x16x32_bf16(a[m], b[n], acc[m][n], 0, 0, 0);
    }
    __syncthreads();
  }

  // epilogue: C/D layout col = lane&15, row = (lane>>4)*4 + r
#pragma unroll
  for (int mi = 0; mi < 4; ++mi) {
#pragma unroll
    for (int ni = 0; ni < 4; ++ni) {
      f32x4 v = acc[mi][ni];
      const int row0 = brow + wr + mi * 16 + (lane >> 4) * 4;
      const int col = bcol + wc + ni * 16 + lrow;
      if constexpr (MODE == 3) {
        float* O = (float*)outp;
        const float bv = bias[col];
#pragma unroll
        for (int r = 0; r < 4; ++r)
          O[(size_t)(row0 + r) * 2048 + col] = v[r] + bv;
      } else if constexpr (MODE == 0 || MODE == 1) {
        u16* O = (u16*)outp;
        const float bv = bias[col];
        const int h = col >> 7, d = col & 127;
        const float sgn = (d & 1) ? 1.f : -1.f;
        const float QSCL = 0.08838834764831845f * 1.44269504088896340f;
#pragma unroll
        for (int r = 0; r < 4; ++r) {
          const int row = row0 + r, bb = row >> 11, s = row & 2047;
          float q = v[r] + bv;
          float p = __shfl_xor(q, 1);   // partner dim d^1 lives in lane^1
          float o = q * cosT[s * 128 + d] + sgn * p * sinT[s * 128 + d];
          if constexpr (MODE == 0) o *= QSCL;
          u16* base = O + ((size_t)(bb * 16 + h) * 2048 + s) * 128;
          if constexpr (MODE == 0) {
            base[d] = f2bf(o);
          } else {
            *(u16*)((char*)base + (((unsigned)(d << 1)) ^ (unsigned)((s & 7) << 4))) = f2bf(o);
          }
        }
      } else { // MODE 2: V -> Vt [B,H,HD,S], pi-permuted within each 64-col block
        u16* O = (u16*)outp;
        const float bv = bias[col];
        const int h = col >> 7, d = col & 127;
        const int bb = row0 >> 11, s = row0 & 2047;
        us4 ov;
#pragma unroll
        for (int r = 0; r < 4; ++r) ov[r] = f2bf(v[r] + bv);
        const int l = s & 63;
        const int kt = l >> 4, g2 = (l >> 2) & 3;
        const int c = ((kt >> 1) << 5) + (g2 << 3) + ((kt & 1) << 2);
        u16* base = O + ((size_t)(bb * 16 + h) * 128 + d) * 2048 + (s & ~63);
        *(us4*)((char*)base + ((unsigned)(c << 1) ^ (unsigned)((d & 7) << 4))) = ov;
      }
    }
  }
}

// -------- causal flash attention: 8-wave blocks, UNCONSTRAINED VGPR ---------
// Q: [BH][S][128] bf16 pre-scaled by 1/sqrt(128)*log2e, K: row-swizzled,
// Vt: [BH][128][S] pi-permuted + swizzled. AO out: [4096][2048] bf16.
// Block = 8 waves x 16 q = 128-row q-tile; folded pairing {p, 15-p} ->
// uniform 34 KV-iters. 512 blocks x 512 thr; LDS 64KB -> 2 blocks/CU =
// 16 waves/CU (4 waves/SIMD, 2x R5 TLP). launch_bounds(512,2): VGPR cap 128
// (R14's (512,4) forced 64 VGPR -> spills -> 156MB scratch writes).
__global__ __launch_bounds__(512, 2)
void attn_fwd(const u16* __restrict__ Q, const u16* __restrict__ K,
              const u16* __restrict__ Vt, u16* __restrict__ AO)
{
  __shared__ __align__(16) u16 Ks[2][64 * 128];
  __shared__ __align__(16) u16 Vs[2][128 * 64];
  const int t = threadIdx.x, w = t >> 6, lane = t & 63;
  const int lrow = lane & 15, g = lane >> 4, lk8 = g * 8;
  const int id = blockIdx.x;
  const int bh = (id & 7) | (((id >> 3) & 3) << 3);   // XCD-local bh grouping
  const int pr = id >> 5;                              // pair index 0..15
  const u16* Qg = Q + (size_t)bh * 2048 * 128;
  const u16* Kg = K + (size_t)bh * 2048 * 128;
  const u16* Vg = Vt + (size_t)bh * 128 * 2048;
  const int bb = bh >> 4, h = bh & 15;

  auto stage = [&](int i, int b) {
#pragma unroll
    for (int r = 0; r < 2; ++r) {
      int e = (r * 512 + t) * 8;
      async16(Kg + (size_t)i * 8192 + e, &Ks[b][e]);
      async16(Vg + (size_t)(e >> 6) * 2048 + i * 64 + (e & 63), &Vs[b][e]);
    }
  };

  for (int half = 0; half < 2; ++half) {
    const int qt = half ? (15 - pr) : pr;     // 128-row q-tile index
    const int qw = qt * 128 + w * 16;         // this wave's 16 q-rows
    const int nkv = 2 * qt + 2;
    const int qg = qw + lrow;                 // this lane's q-row

    bf16x8 qf[4];
#pragma unroll
    for (int c = 0; c < 4; ++c)
      qf[c] = *(const bf16x8*)(Qg + (size_t)(qw + lrow) * 128 + lk8 + c * 32);

    f32x4 acc_o[8] = {};
    float m = -1e30f, lsum = 0.f;

    stage(0, 0);
    for (int i = 0; i < nkv; ++i) {
      const int cur = i & 1;
      const bool pfch = (i + 1) < nkv;
      if (pfch) stage(i + 1, cur ^ 1);
      if (pfch) asm volatile("s_waitcnt vmcnt(4)" ::: "memory");
      else      asm volatile("s_waitcnt vmcnt(0)" ::: "memory");
      __builtin_amdgcn_s_barrier();
      __builtin_amdgcn_sched_barrier(0);

      // QK^T swapped: C col = q (lane&15), row = k
      f32x4 sc[4];
      __builtin_amdgcn_s_setprio(1);
#pragma unroll
      for (int kt = 0; kt < 4; ++kt) {
        f32x4 s = {};
        const int krow = kt * 16 + lrow;
        const char* kbase = (const char*)(&Ks[cur][krow * 128]);
        const unsigned sw = (unsigned)((krow & 7) << 4);
#pragma unroll
        for (int c = 0; c < 4; ++c) {
          bf16x8 kf = *(const bf16x8*)(kbase + ((unsigned)((lk8 + c * 32) << 1) ^ sw));
          s = __builtin_amdgcn_mfma_f32_16x16x32_bf16(kf, qf[c], s, 0, 0, 0);
        }
        sc[kt] = s;
      }
      __builtin_amdgcn_s_setprio(0);

      float p[4][4];
      const bool guard = (i * 64 + 63) > qw;   // kv-tile reaches this wave's rows
      if (guard) {
#pragma unroll
        for (int kt = 0; kt < 4; ++kt)
#pragma unroll
          for (int r = 0; r < 4; ++r) {
            int kg = i * 64 + kt * 16 + g * 4 + r;
            p[kt][r] = (kg > qg) ? -1e30f : sc[kt][r];
          }
      } else {
#pragma unroll
        for (int kt = 0; kt < 4; ++kt)
#pragma unroll
          for (int r = 0; r < 4; ++r) p[kt][r] = sc[kt][r];
      }

      float mm = p[0][0];
#pragma unroll
      for (int kt = 0; kt < 4; ++kt)
#pragma unroll
        for (int r = 0; r < 4; ++r) mm = fmaxf(mm, p[kt][r]);
      mm = fmaxf(mm, __shfl_xor(mm, 16));
      mm = fmaxf(mm, __shfl_xor(mm, 32));

      float rs = 0.f;
      if (__any(mm > m + 8.f)) {
        const float mn = fmaxf(m, mm);
        const float corr = exp2f(m - mn);
        m = mn;
#pragma unroll
        for (int kt = 0; kt < 4; ++kt)
#pragma unroll
          for (int r = 0; r < 4; ++r) { p[kt][r] = exp2f(p[kt][r] - m); rs += p[kt][r]; }
        rs += __shfl_xor(rs, 16);
        rs += __shfl_xor(rs, 32);
        lsum = lsum * corr + rs;
#pragma unroll
        for (int nt = 0; nt < 8; ++nt)
#pragma unroll
          for (int r = 0; r < 4; ++r) acc_o[nt][r] *= corr;
      } else {
#pragma unroll
        for (int kt = 0; kt < 4; ++kt)
#pragma unroll
          for (int r = 0; r < 4; ++r) { p[kt][r] = exp2f(p[kt][r] - m); rs += p[kt][r]; }
        rs += __shfl_xor(rs, 16);
        rs += __shfl_xor(rs, 32);
        lsum += rs;
      }

      bf16x8 pb[2];
#pragma unroll
      for (int kc = 0; kc < 2; ++kc) {
        union { u32 d[4]; bf16x8 v; } u;
        u.d[0] = pkbf(p[2 * kc][0], p[2 * kc][1]);
        u.d[1] = pkbf(p[2 * kc][2], p[2 * kc][3]);
        u.d[2] = pkbf(p[2 * kc + 1][0], p[2 * kc + 1][1]);
        u.d[3] = pkbf(p[2 * kc + 1][2], p[2 * kc + 1][3]);
        pb[kc] = u.v;
      }

      __builtin_amdgcn_s_setprio(1);
#pragma unroll
      for (int nt = 0; nt < 8; ++nt) {
        const int vrow = nt * 16 + lrow;
        const char* vbase = (const char*)(&Vs[cur][vrow * 64]);
        const unsigned sw2 = (unsigned)((vrow & 7) << 4);
#pragma unroll
        for (int kc = 0; kc < 2; ++kc) {
          bf16x8 vf = *(const bf16x8*)(vbase + ((unsigned)((lk8 + kc * 32) << 1) ^ sw2));
          acc_o[nt] = __builtin_amdgcn_mfma_f32_16x16x32_bf16(vf, pb[kc], acc_o[nt], 0, 0, 0);
        }
      }
      __builtin_amdgcn_s_setprio(0);
      __builtin_amdgcn_s_barrier();
    }

    const float inv_l = 1.f / lsum;
#pragma unroll
    for (int nt = 0; nt < 8; ++nt) {
      us4 ov;
#pragma unroll
      for (int r = 0; r < 4; ++r) ov[r] = f2bf(acc_o[nt][r] * inv_l);
      *(us4*)(AO + ((size_t)(bb * 2048 + qg)) * 2048 + h * 128 + nt * 16 + g * 4) = ov;
    }
  }
}

// ---------------- launch ----------------
extern "C" void kernel_launch(void* const* d_in, const int* in_sizes, int n_in,
                              void* d_out, int out_size, void* d_ws, size_t ws_size,
                              hipStream_t stream) {
  const float* x    = (const float*)d_in[0];
  const float* cosT = (const float*)d_in[1];
  const float* sinT = (const float*)d_in[2];
  const float* Wq   = (const float*)d_in[4];
  const float* bq   = (const float*)d_in[5];
  const float* Wk   = (const float*)d_in[6];
  const float* bk   = (const float*)d_in[7];
  const float* Wv   = (const float*)d_in[8];
  const float* bv   = (const float*)d_in[9];
  const float* Wo   = (const float*)d_in[10];
  const float* bo   = (const float*)d_in[11];
  float* out = (float*)d_out;

  char* ws = (char*)d_ws;
  u16* xb  = (u16*)(ws);                    // 16 MB  [4096][2048]
  u16* Wqb = (u16*)(ws + (16u << 20));      // 8 MB
  u16* Wkb = (u16*)(ws + (24u << 20));
  u16* Wvb = (u16*)(ws + (32u << 20));
  u16* Wob = (u16*)(ws + (40u << 20));
  u16* Qb  = (u16*)(ws + (48u << 20));      // 16 MB [BH][S][HD] (pre-scaled)
  u16* Kb  = (u16*)(ws + (64u << 20));      // 16 MB [BH][S][HD] swizzled
  u16* Vtb = (u16*)(ws + (80u << 20));      // 16 MB [BH][HD][S] permuted+swizzled
  u16* AOb = (u16*)(ws + (96u << 20));      // 16 MB [4096][2048]

  // one fused cast: x + 4 weights (25.17M elems / 4 per thread)
  cast_all<<<24576, 256, 0, stream>>>(x, Wq, Wk, Wv, Wo, xb, Wqb, Wkb, Wvb, Wob);

  dim3 gg(16, 32);  // N/128, M/128
  gemm_bt<0><<<gg, 256, 0, stream>>>(xb, Wqb, bq, cosT, sinT, (void*)Qb);
  gemm_bt<1><<<gg, 256, 0, stream>>>(xb, Wkb, bk, cosT, sinT, (void*)Kb);
  gemm_bt<2><<<gg, 256, 0, stream>>>(xb, Wvb, bv, nullptr, nullptr, (void*)Vtb);

  attn_fwd<<<512, 512, 0, stream>>>(Qb, Kb, Vtb, AOb);

  gemm_bt<3><<<gg, 256, 0, stream>>>(AOb, Wob, bo, nullptr, nullptr, (void*)out);
}

// Round 17
// 247.552 us; speedup vs baseline: 1.4631x; 1.2825x over previous
//
#include <hip/hip_runtime.h>
#include <math.h>

typedef __attribute__((ext_vector_type(8))) __bf16 bf16x8;
typedef __attribute__((ext_vector_type(4))) float f32x4;
typedef __attribute__((ext_vector_type(4))) unsigned short us4;
typedef unsigned short u16;
typedef unsigned int u32;

#define DEVI static __device__ __forceinline__

// round-to-nearest-even fp32 -> bf16
DEVI u16 f2bf(float f) {
  union { float f; unsigned u; } v; v.f = f;
  unsigned r = v.u + 0x7fffu + ((v.u >> 16) & 1u);
  return (u16)(r >> 16);
}

DEVI void async16(const void* g, void* l) {
  __builtin_amdgcn_global_load_lds((const __attribute__((address_space(1))) void*)g,
                                   (__attribute__((address_space(3))) void*)l, 16, 0, 0);
}

// pack two f32 -> one u32 of 2 bf16 (RNE)
DEVI u32 pkbf(float lo, float hi) {
  u32 r;
  asm("v_cvt_pk_bf16_f32 %0, %1, %2" : "=v"(r) : "v"(lo), "v"(hi));
  return r;
}

// ---------------- fused cast fp32 -> bf16 (x + 4 weights, one launch) -------
__global__ __launch_bounds__(256)
void cast_all(const float* __restrict__ x,
              const float* __restrict__ wq, const float* __restrict__ wk,
              const float* __restrict__ wv, const float* __restrict__ wo,
              u16* __restrict__ xb, u16* __restrict__ wqb, u16* __restrict__ wkb,
              u16* __restrict__ wvb, u16* __restrict__ wob)
{
  const int NX = 4096 * 2048, NW = 2048 * 2048;
  int i = (blockIdx.x * 256 + threadIdx.x) * 4;
  const float* src; u16* dst; int off;
  if (i < NX)               { src = x;  dst = xb;  off = i; }
  else if (i < NX + NW)     { src = wq; dst = wqb; off = i - NX; }
  else if (i < NX + 2 * NW) { src = wk; dst = wkb; off = i - NX - NW; }
  else if (i < NX + 3 * NW) { src = wv; dst = wvb; off = i - NX - 2 * NW; }
  else                      { src = wo; dst = wob; off = i - NX - 3 * NW; }
  float4 v = *(const float4*)(src + off);
  us4 o = { f2bf(v.x), f2bf(v.y), f2bf(v.z), f2bf(v.w) };
  *(us4*)(dst + off) = o;
}

// ---------------- GEMM: C[m,n] = sum_k A[m,k]*B[n,k] (+bias) ----------------
// m97 template, BK=64 (R11-proven ~37us): 128x128 tile, 4 waves, 2-barrier
// K-loop, global_load_lds width-16, LDS [128][64] XOR-swizzled (row&7)<<4
// via inverse-swizzled GLOBAL source + linear LDS dest (G21).
// MODE 0: Q -> rope*(1/sqrt(128)*log2e); 1: K rope+swz; 2: V transp+perm+swz;
// MODE 3: O -> fp32 + bias
template<int MODE>
__global__ __launch_bounds__(256, 3)
void gemm_bt(const u16* __restrict__ A, const u16* __restrict__ B,
             const float* __restrict__ bias,
             const float* __restrict__ cosT, const float* __restrict__ sinT,
             void* __restrict__ outp)
{
  __shared__ __align__(16) u16 As[8192];   // [128][64] swizzled
  __shared__ __align__(16) u16 Bs[8192];
  const int t = threadIdx.x, w = t >> 6, lane = t & 63;
  const int lrow = lane & 15, lk8 = (lane >> 4) * 8;
  const int brow = blockIdx.y * 128, bcol = blockIdx.x * 128;
  const int wr = (w >> 1) * 64, wc = (w & 1) * 64;

  u32 sA[4], sB[4];
#pragma unroll
  for (int r = 0; r < 4; ++r) {
    const int q = (r * 256 + t) * 16;
    const int row = q >> 7;
    const int cb = (q ^ ((row & 7) << 4)) & 127;   // logical col byte
    sA[r] = (u32)((brow + row) * 2048 + (cb >> 1));
    sB[r] = (u32)((bcol + row) * 2048 + (cb >> 1));
  }

  int offA[4][2], offB[4][2];
#pragma unroll
  for (int m = 0; m < 4; ++m)
#pragma unroll
    for (int kk = 0; kk < 2; ++kk) {
      int row = wr + m * 16 + lrow;
      offA[m][kk] = (row * 128 + (kk * 32 + lk8) * 2) ^ ((row & 7) << 4);
      row = wc + m * 16 + lrow;
      offB[m][kk] = (row * 128 + (kk * 32 + lk8) * 2) ^ ((row & 7) << 4);
    }

  f32x4 acc[4][4] = {};

  for (int k0 = 0; k0 < 2048; k0 += 64) {
#pragma unroll
    for (int r = 0; r < 4; ++r) {
      async16(A + sA[r] + k0, (char*)As + (r * 256 + t) * 16);
      async16(B + sB[r] + k0, (char*)Bs + (r * 256 + t) * 16);
    }
    __syncthreads();
#pragma unroll
    for (int kk = 0; kk < 2; ++kk) {
      bf16x8 a[4], b[4];
#pragma unroll
      for (int m = 0; m < 4; ++m) a[m] = *(const bf16x8*)((char*)As + offA[m][kk]);
#pragma unroll
      for (int n = 0; n < 4; ++n) b[n] = *(const bf16x8*)((char*)Bs + offB[n][kk]);
#pragma unroll
      for (int m = 0; m < 4; ++m)
#pragma unroll
        for (int n = 0; n < 4; ++n)
          acc[m][n] = __builtin_amdgcn_mfma_f32_16x16x32_bf16(a[m], b[n], acc[m][n], 0, 0, 0);
    }
    __syncthreads();
  }

  // epilogue: C/D layout col = lane&15, row = (lane>>4)*4 + r
#pragma unroll
  for (int mi = 0; mi < 4; ++mi) {
#pragma unroll
    for (int ni = 0; ni < 4; ++ni) {
      f32x4 v = acc[mi][ni];
      const int row0 = brow + wr + mi * 16 + (lane >> 4) * 4;
      const int col = bcol + wc + ni * 16 + lrow;
      if constexpr (MODE == 3) {
        float* O = (float*)outp;
        const float bv = bias[col];
#pragma unroll
        for (int r = 0; r < 4; ++r)
          O[(size_t)(row0 + r) * 2048 + col] = v[r] + bv;
      } else if constexpr (MODE == 0 || MODE == 1) {
        u16* O = (u16*)outp;
        const float bv = bias[col];
        const int h = col >> 7, d = col & 127;
        const float sgn = (d & 1) ? 1.f : -1.f;
        const float QSCL = 0.08838834764831845f * 1.44269504088896340f;
#pragma unroll
        for (int r = 0; r < 4; ++r) {
          const int row = row0 + r, bb = row >> 11, s = row & 2047;
          float q = v[r] + bv;
          float p = __shfl_xor(q, 1);   // partner dim d^1 lives in lane^1
          float o = q * cosT[s * 128 + d] + sgn * p * sinT[s * 128 + d];
          if constexpr (MODE == 0) o *= QSCL;
          u16* base = O + ((size_t)(bb * 16 + h) * 2048 + s) * 128;
          if constexpr (MODE == 0) {
            base[d] = f2bf(o);
          } else {
            *(u16*)((char*)base + (((unsigned)(d << 1)) ^ (unsigned)((s & 7) << 4))) = f2bf(o);
          }
        }
      } else { // MODE 2: V -> Vt [B,H,HD,S], pi-permuted within each 64-col block
        u16* O = (u16*)outp;
        const float bv = bias[col];
        const int h = col >> 7, d = col & 127;
        const int bb = row0 >> 11, s = row0 & 2047;
        us4 ov;
#pragma unroll
        for (int r = 0; r < 4; ++r) ov[r] = f2bf(v[r] + bv);
        const int l = s & 63;
        const int kt = l >> 4, g2 = (l >> 2) & 3;
        const int c = ((kt >> 1) << 5) + (g2 << 3) + ((kt & 1) << 2);
        u16* base = O + ((size_t)(bb * 16 + h) * 128 + d) * 2048 + (s & ~63);
        *(us4*)((char*)base + ((unsigned)(c << 1) ^ (unsigned)((d & 7) << 4))) = ov;
      }
    }
  }
}

// ---------------- causal flash attention (R5-proven, 75us) ----------------
// Q: [BH][S][128] bf16 pre-scaled by 1/sqrt(128)*log2e, K: row-swizzled,
// Vt: [BH][128][S] pi-permuted + swizzled. AO out: [4096][2048] bf16.
// 512 blocks (2/CU), folded pairing {p, 31-p} -> uniform 33 KV-iters.
__global__ __launch_bounds__(256, 2)
void attn_fwd(const u16* __restrict__ Q, const u16* __restrict__ K,
              const u16* __restrict__ Vt, u16* __restrict__ AO)
{
  __shared__ __align__(16) u16 Ks[2][64 * 128];
  __shared__ __align__(16) u16 Vs[2][128 * 64];
  const int t = threadIdx.x, w = t >> 6, lane = t & 63;
  const int lrow = lane & 15, g = lane >> 4, lk8 = g * 8;
  const int id = blockIdx.x;
  const int bh = (id & 7) | (((id >> 3) & 3) << 3);   // XCD-local bh grouping
  const int pr = id >> 5;                              // pair index 0..15
  const u16* Qg = Q + (size_t)bh * 2048 * 128;
  const u16* Kg = K + (size_t)bh * 2048 * 128;
  const u16* Vg = Vt + (size_t)bh * 128 * 2048;
  const int bb = bh >> 4, h = bh & 15;

  for (int half = 0; half < 2; ++half) {
    const int qt = half ? (31 - pr) : pr;
    const int q0 = qt * 64, qw = q0 + w * 16;
    const int nkv = qt + 1;
    const int qg = qw + lrow;   // this lane's q-row

    bf16x8 qf[4];
#pragma unroll
    for (int c = 0; c < 4; ++c)
      qf[c] = *(const bf16x8*)(Qg + (size_t)(qw + lrow) * 128 + lk8 + c * 32);

    f32x4 acc_o[8] = {};
    float m = -1e30f, lsum = 0.f;

    auto stage = [&](int i, int b) {
#pragma unroll
      for (int r = 0; r < 4; ++r) {
        int e = (r * 256 + t) * 8;
        async16(Kg + (size_t)i * 8192 + e, &Ks[b][r * 2048 + w * 512]);
        async16(Vg + (size_t)(e >> 6) * 2048 + i * 64 + (e & 63), &Vs[b][r * 2048 + w * 512]);
      }
    };

    stage(0, 0);
    for (int i = 0; i < nkv; ++i) {
      const int cur = i & 1;
      const bool pfch = (i + 1) < nkv;
      if (pfch) stage(i + 1, cur ^ 1);
      if (pfch) asm volatile("s_waitcnt vmcnt(8)" ::: "memory");
      else      asm volatile("s_waitcnt vmcnt(0)" ::: "memory");
      __builtin_amdgcn_s_barrier();
      __builtin_amdgcn_sched_barrier(0);

      // QK^T swapped: C col = q (lane&15), row = k
      f32x4 sc[4];
      __builtin_amdgcn_s_setprio(1);
#pragma unroll
      for (int kt = 0; kt < 4; ++kt) {
        f32x4 s = {};
        const int krow = kt * 16 + lrow;
        const char* kbase = (const char*)(&Ks[cur][krow * 128]);
        const unsigned sw = (unsigned)((krow & 7) << 4);
#pragma unroll
        for (int c = 0; c < 4; ++c) {
          bf16x8 kf = *(const bf16x8*)(kbase + ((unsigned)((lk8 + c * 32) << 1) ^ sw));
          s = __builtin_amdgcn_mfma_f32_16x16x32_bf16(kf, qf[c], s, 0, 0, 0);
        }
        sc[kt] = s;
      }
      __builtin_amdgcn_s_setprio(0);

      float p[4][4];
      const bool lastblk = (i == qt);
      if (lastblk) {
#pragma unroll
        for (int kt = 0; kt < 4; ++kt)
#pragma unroll
          for (int r = 0; r < 4; ++r) {
            int kg = i * 64 + kt * 16 + g * 4 + r;
            p[kt][r] = (kg > qg) ? -1e30f : sc[kt][r];
          }
      } else {
#pragma unroll
        for (int kt = 0; kt < 4; ++kt)
#pragma unroll
          for (int r = 0; r < 4; ++r) p[kt][r] = sc[kt][r];
      }

      float mm = p[0][0];
#pragma unroll
      for (int kt = 0; kt < 4; ++kt)
#pragma unroll
        for (int r = 0; r < 4; ++r) mm = fmaxf(mm, p[kt][r]);
      mm = fmaxf(mm, __shfl_xor(mm, 16));
      mm = fmaxf(mm, __shfl_xor(mm, 32));

      float rs = 0.f;
      if (__any(mm > m + 8.f)) {
        const float mn = fmaxf(m, mm);
        const float corr = exp2f(m - mn);
        m = mn;
#pragma unroll
        for (int kt = 0; kt < 4; ++kt)
#pragma unroll
          for (int r = 0; r < 4; ++r) { p[kt][r] = exp2f(p[kt][r] - m); rs += p[kt][r]; }
        rs += __shfl_xor(rs, 16);
        rs += __shfl_xor(rs, 32);
        lsum = lsum * corr + rs;
#pragma unroll
        for (int nt = 0; nt < 8; ++nt)
#pragma unroll
          for (int r = 0; r < 4; ++r) acc_o[nt][r] *= corr;
      } else {
#pragma unroll
        for (int kt = 0; kt < 4; ++kt)
#pragma unroll
          for (int r = 0; r < 4; ++r) { p[kt][r] = exp2f(p[kt][r] - m); rs += p[kt][r]; }
        rs += __shfl_xor(rs, 16);
        rs += __shfl_xor(rs, 32);
        lsum += rs;
      }

      bf16x8 pb[2];
#pragma unroll
      for (int kc = 0; kc < 2; ++kc) {
        union { u32 d[4]; bf16x8 v; } u;
        u.d[0] = pkbf(p[2 * kc][0], p[2 * kc][1]);
        u.d[1] = pkbf(p[2 * kc][2], p[2 * kc][3]);
        u.d[2] = pkbf(p[2 * kc + 1][0], p[2 * kc + 1][1]);
        u.d[3] = pkbf(p[2 * kc + 1][2], p[2 * kc + 1][3]);
        pb[kc] = u.v;
      }

      __builtin_amdgcn_s_setprio(1);
#pragma unroll
      for (int nt = 0; nt < 8; ++nt) {
        const int vrow = nt * 16 + lrow;
        const char* vbase = (const char*)(&Vs[cur][vrow * 64]);
        const unsigned sw2 = (unsigned)((vrow & 7) << 4);
#pragma unroll
        for (int kc = 0; kc < 2; ++kc) {
          bf16x8 vf = *(const bf16x8*)(vbase + ((unsigned)((lk8 + kc * 32) << 1) ^ sw2));
          acc_o[nt] = __builtin_amdgcn_mfma_f32_16x16x32_bf16(vf, pb[kc], acc_o[nt], 0, 0, 0);
        }
      }
      __builtin_amdgcn_s_setprio(0);
      __builtin_amdgcn_s_barrier();
    }

    const float inv_l = 1.f / lsum;
#pragma unroll
    for (int nt = 0; nt < 8; ++nt) {
      us4 ov;
#pragma unroll
      for (int r = 0; r < 4; ++r) ov[r] = f2bf(acc_o[nt][r] * inv_l);
      *(us4*)(AO + ((size_t)(bb * 2048 + qg)) * 2048 + h * 128 + nt * 16 + g * 4) = ov;
    }
  }
}

// ---------------- launch ----------------
extern "C" void kernel_launch(void* const* d_in, const int* in_sizes, int n_in,
                              void* d_out, int out_size, void* d_ws, size_t ws_size,
                              hipStream_t stream) {
  const float* x    = (const float*)d_in[0];
  const float* cosT = (const float*)d_in[1];
  const float* sinT = (const float*)d_in[2];
  const float* Wq   = (const float*)d_in[4];
  const float* bq   = (const float*)d_in[5];
  const float* Wk   = (const float*)d_in[6];
  const float* bk   = (const float*)d_in[7];
  const float* Wv   = (const float*)d_in[8];
  const float* bv   = (const float*)d_in[9];
  const float* Wo   = (const float*)d_in[10];
  const float* bo   = (const float*)d_in[11];
  float* out = (float*)d_out;

  char* ws = (char*)d_ws;
  u16* xb  = (u16*)(ws);                    // 16 MB  [4096][2048]
  u16* Wqb = (u16*)(ws + (16u << 20));      // 8 MB
  u16* Wkb = (u16*)(ws + (24u << 20));
  u16* Wvb = (u16*)(ws + (32u << 20));
  u16* Wob = (u16*)(ws + (40u << 20));
  u16* Qb  = (u16*)(ws + (48u << 20));      // 16 MB [BH][S][HD] (pre-scaled)
  u16* Kb  = (u16*)(ws + (64u << 20));      // 16 MB [BH][S][HD] swizzled
  u16* Vtb = (u16*)(ws + (80u << 20));      // 16 MB [BH][HD][S] permuted+swizzled
  u16* AOb = (u16*)(ws + (96u << 20));      // 16 MB [4096][2048]

  // one fused cast: x + 4 weights (25.17M elems / 4 per thread)
  cast_all<<<24576, 256, 0, stream>>>(x, Wq, Wk, Wv, Wo, xb, Wqb, Wkb, Wvb, Wob);

  dim3 gg(16, 32);  // N/128, M/128
  gemm_bt<0><<<gg, 256, 0, stream>>>(xb, Wqb, bq, cosT, sinT, (void*)Qb);
  gemm_bt<1><<<gg, 256, 0, stream>>>(xb, Wkb, bk, cosT, sinT, (void*)Kb);
  gemm_bt<2><<<gg, 256, 0, stream>>>(xb, Wvb, bv, nullptr, nullptr, (void*)Vtb);

  attn_fwd<<<512, 256, 0, stream>>>(Qb, Kb, Vtb, AOb);

  gemm_bt<3><<<gg, 256, 0, stream>>>(AOb, Wob, bo, nullptr, nullptr, (void*)out);
}